// Round 1
// baseline (1378.724 us; speedup 1.0000x reference)
//
#include <hip/hip_runtime.h>
#include <cmath>

#define BATCH   16384
#define NT      26
#define VOCAB_N 100000
#define EMB_D   64
#define LOOK    4

// ---------------------------------------------------------------------------
// Generic fp32 GEMM: Y[m][n] = act( sum_k X[m][k] * W[n][k] + bias[n] )
// X: M x K row-major, W: N x K row-major (i.e. Y = X @ W^T + b).
// 256 threads, BK=16, thread computes TM x TN micro-tile.
// M % BM == 0 and N % BN == 0 are required (true for all call sites).
// K is arbitrary (zero-padded in LDS).
// ---------------------------------------------------------------------------
template<int BM, int BN, int TM, int TN, int RELU>
__global__ __launch_bounds__(256) void gemm_relu(
    const float* __restrict__ X, const float* __restrict__ W,
    const float* __restrict__ bias, float* __restrict__ Y,
    int M, int N, int K)
{
    constexpr int BK  = 16;
    constexpr int PAD = 4;                       // keep rows 16B-aligned, break pow2 stride
    __shared__ __align__(16) float Xs[BK][BM + PAD];
    __shared__ __align__(16) float Ws[BK][BN + PAD];

    const int tid = threadIdx.x;
    const int tx  = tid % (BN / TN);             // column group
    const int ty  = tid / (BN / TN);             // row group
    const int m0  = blockIdx.y * BM;
    const int n0  = blockIdx.x * BN;

    float acc[TM][TN];
    #pragma unroll
    for (int i = 0; i < TM; i++)
        #pragma unroll
        for (int j = 0; j < TN; j++) acc[i][j] = 0.f;

    for (int k0 = 0; k0 < K; k0 += BK) {
        // stage X tile (BM x BK) transposed into Xs[k][r]
        for (int idx = tid; idx < BM * BK; idx += 256) {
            int r = idx / BK, k = idx % BK;
            int gk = k0 + k;
            Xs[k][r] = (gk < K) ? X[(size_t)(m0 + r) * K + gk] : 0.f;
        }
        // stage W tile (BN x BK) transposed into Ws[k][c]
        for (int idx = tid; idx < BN * BK; idx += 256) {
            int r = idx / BK, k = idx % BK;
            int gk = k0 + k;
            Ws[k][r] = (gk < K) ? W[(size_t)(n0 + r) * K + gk] : 0.f;
        }
        __syncthreads();

        #pragma unroll
        for (int kk = 0; kk < BK; kk++) {
            float a[TM], bb[TN];
            #pragma unroll
            for (int i = 0; i < TM; i++) a[i] = Xs[kk][ty * TM + i];
            #pragma unroll
            for (int j = 0; j < TN; j++) bb[j] = Ws[kk][tx * TN + j];
            #pragma unroll
            for (int i = 0; i < TM; i++)
                #pragma unroll
                for (int j = 0; j < TN; j++)
                    acc[i][j] += a[i] * bb[j];
        }
        __syncthreads();
    }

    // epilogue: bias + optional relu; TN consecutive columns per thread
    #pragma unroll
    for (int i = 0; i < TM; i++) {
        int m = m0 + ty * TM + i;
        #pragma unroll
        for (int j = 0; j < TN; j++) {
            int n = n0 + tx * TN + j;
            float v = acc[i][j] + bias[n];
            if (RELU) v = fmaxf(v, 0.f);
            Y[(size_t)m * N + n] = v;
        }
    }
}

// ---------------------------------------------------------------------------
// Embedding gather + pairwise interaction. One block (256 threads) per sample.
// Builds Tmat (27 x 64) in LDS: row 0 = bottom-MLP output x2, rows 1..26 =
// per-table sum of 4 embedding rows. Emits R row = [x2 (64) | lower-tri Gram
// (351)] of width 415.
// ---------------------------------------------------------------------------
#define TS 68   // LDS row stride (floats): 16B-aligned, breaks 32-bank aliasing

__global__ __launch_bounds__(256) void interact_kernel(
    const float* __restrict__ x2,    // B x 64
    const int*   __restrict__ lS_i,  // NT x (B*LOOK)
    const float* __restrict__ emb,   // NT x VOCAB x 64
    float* __restrict__ R)           // B x 415
{
    __shared__ __align__(16) float T[(NT + 1) * TS];
    __shared__ int sidx[NT * LOOK];

    const int b   = blockIdx.x;
    const int tid = threadIdx.x;

    if (tid < NT * LOOK) {
        int tb = tid >> 2, l = tid & 3;
        sidx[tid] = lS_i[(size_t)tb * (BATCH * LOOK) + (size_t)b * LOOK + l];
    }
    if (tid < EMB_D) T[tid] = x2[(size_t)b * EMB_D + tid];
    __syncthreads();

    // gather: wave w handles tables w, w+4, ... ; lane d reads element d
    const int d = tid & 63;
    for (int tb = tid >> 6; tb < NT; tb += 4) {
        float s = 0.f;
        #pragma unroll
        for (int l = 0; l < LOOK; l++) {
            int row = sidx[tb * LOOK + l];
            s += emb[((size_t)tb * VOCAB_N + row) * EMB_D + d];
        }
        T[(tb + 1) * TS + d] = s;
    }
    __syncthreads();

    float* Rb = R + (size_t)b * 415;
    if (tid < EMB_D) Rb[tid] = T[tid];

    // 351 lower-tri pairs in reference order: (i,j), i in [1,27), j in [0,i)
    for (int p = tid; p < 351; p += 256) {
        int i = (int)((1.0f + sqrtf(1.0f + 8.0f * (float)p)) * 0.5f);
        while (i * (i - 1) / 2 > p) --i;
        while ((i + 1) * i / 2 <= p) ++i;
        int j = p - i * (i - 1) / 2;
        const float* Ti = &T[i * TS];
        const float* Tj = &T[j * TS];
        float s = 0.f;
        #pragma unroll
        for (int k = 0; k < EMB_D; k++) s += Ti[k] * Tj[k];
        Rb[64 + p] = s;
    }
}

// ---------------------------------------------------------------------------
// Final layer: out[b] = sigmoid( dot(z1[b,:256], W2) + b2 ). Wave per sample.
// ---------------------------------------------------------------------------
__global__ __launch_bounds__(256) void top_final(
    const float* __restrict__ z1, const float* __restrict__ W2,
    const float* __restrict__ b2, float* __restrict__ out)
{
    const int wave = threadIdx.x >> 6;
    const int lane = threadIdx.x & 63;
    const int b = blockIdx.x * 4 + wave;

    float s = 0.f;
    #pragma unroll
    for (int q = 0; q < 4; q++) {
        int k = q * 64 + lane;
        s += z1[(size_t)b * 256 + k] * W2[k];
    }
    #pragma unroll
    for (int off = 32; off; off >>= 1) s += __shfl_down(s, off, 64);
    if (lane == 0) {
        float v = s + b2[0];
        out[b] = 1.f / (1.f + expf(-v));
    }
}

// ---------------------------------------------------------------------------
// setup_inputs() dict order (note bot/top interleaving!):
//  0 dense_x  1 lS_o  2 lS_i  3 emb
//  4 bot_W0  5 bot_b0   6 top_W0  7 top_b0
//  8 bot_W1  9 bot_b1  10 top_W1 11 top_b1
// 12 bot_W2 13 bot_b2  14 top_W2 15 top_b2
// ---------------------------------------------------------------------------
extern "C" void kernel_launch(void* const* d_in, const int* in_sizes, int n_in,
                              void* d_out, int out_size, void* d_ws, size_t ws_size,
                              hipStream_t stream)
{
    const float* dense = (const float*)d_in[0];
    const int*   lS_i  = (const int*)d_in[2];
    const float* emb   = (const float*)d_in[3];
    const float* bW0 = (const float*)d_in[4];  const float* bb0 = (const float*)d_in[5];
    const float* tW0 = (const float*)d_in[6];  const float* tb0 = (const float*)d_in[7];
    const float* bW1 = (const float*)d_in[8];  const float* bb1 = (const float*)d_in[9];
    const float* tW1 = (const float*)d_in[10]; const float* tb1 = (const float*)d_in[11];
    const float* bW2 = (const float*)d_in[12]; const float* bb2 = (const float*)d_in[13];
    const float* tW2 = (const float*)d_in[14]; const float* tb2 = (const float*)d_in[15];
    float* out = (float*)d_out;

    // workspace layout (fp32):
    float* buf_a = (float*)d_ws;                       // B*512  (x0, later z0)
    float* buf_b = buf_a + (size_t)BATCH * 512;        // B*256  (x1, later z1)
    float* buf_c = buf_b + (size_t)BATCH * 256;        // B*64   (x2)
    float* buf_R = buf_c + (size_t)BATCH * 64;         // B*415  (interaction out)

    dim3 blk(256);

    // bottom MLP
    gemm_relu<128,128,8,8,1><<<dim3(512/128, BATCH/128), blk, 0, stream>>>(
        dense, bW0, bb0, buf_a, BATCH, 512, 13);
    gemm_relu<128,128,8,8,1><<<dim3(256/128, BATCH/128), blk, 0, stream>>>(
        buf_a, bW1, bb1, buf_b, BATCH, 256, 512);
    gemm_relu<128,64,8,4,1><<<dim3(1, BATCH/128), blk, 0, stream>>>(
        buf_b, bW2, bb2, buf_c, BATCH, 64, 256);

    // embedding + interaction
    interact_kernel<<<dim3(BATCH), blk, 0, stream>>>(buf_c, lS_i, emb, buf_R);

    // top MLP
    gemm_relu<128,128,8,8,1><<<dim3(512/128, BATCH/128), blk, 0, stream>>>(
        buf_R, tW0, tb0, buf_a, BATCH, 512, 415);
    gemm_relu<128,128,8,8,1><<<dim3(256/128, BATCH/128), blk, 0, stream>>>(
        buf_a, tW1, tb1, buf_b, BATCH, 256, 512);
    top_final<<<dim3(BATCH/4), blk, 0, stream>>>(buf_b, tW2, tb2, out);
}

// Round 2
// 905.040 us; speedup vs baseline: 1.5234x; 1.5234x over previous
//
#include <hip/hip_runtime.h>
#include <hip/hip_bf16.h>
#include <cmath>

#define BATCH   16384
#define NT      26
#define VOCAB_N 100000
#define EMB_D   64
#define LOOK    4

typedef __attribute__((ext_vector_type(8))) short  short8;   // 8 bf16 = 4 VGPRs
typedef __attribute__((ext_vector_type(4))) float  float4v;  // MFMA C/D frag

#define GLOBAL_AS __attribute__((address_space(1)))
#define LDS_AS    __attribute__((address_space(3)))

// ---------------------------------------------------------------------------
// fp32 → bf16 weight conversion (optionally K-padded)
// ---------------------------------------------------------------------------
__global__ __launch_bounds__(256) void conv_bf16(
    const float* __restrict__ in, __hip_bfloat16* __restrict__ out, int n)
{
    int i = blockIdx.x * 256 + threadIdx.x;
    if (i < n) out[i] = __float2bfloat16(in[i]);
}

__global__ __launch_bounds__(256) void conv_bf16_pad(
    const float* __restrict__ in, __hip_bfloat16* __restrict__ out,
    int N, int Kin, int Kout)
{
    int i = blockIdx.x * 256 + threadIdx.x;
    if (i < N * Kout) {
        int r = i / Kout, k = i % Kout;
        out[i] = __float2bfloat16(k < Kin ? in[(size_t)r * Kin + k] : 0.f);
    }
}

// ---------------------------------------------------------------------------
// fp32 vector GEMM (small K only: bottom layer 0, K=13), bf16 output.
// Y = relu(X @ W^T + b).  BM=128, BN=128, TM=TN=8, BK=16.
// ---------------------------------------------------------------------------
__global__ __launch_bounds__(256) void gemm_f32_k13(
    const float* __restrict__ X, const float* __restrict__ W,
    const float* __restrict__ bias, __hip_bfloat16* __restrict__ Y,
    int M, int N, int K)
{
    constexpr int BM = 128, BN = 128, BK = 16, TM = 8, TN = 8, PAD = 4;
    __shared__ __align__(16) float Xs[BK][BM + PAD];
    __shared__ __align__(16) float Ws[BK][BN + PAD];

    const int tid = threadIdx.x;
    const int tx  = tid % (BN / TN);
    const int ty  = tid / (BN / TN);
    const int m0  = blockIdx.y * BM;
    const int n0  = blockIdx.x * BN;

    float acc[TM][TN];
    #pragma unroll
    for (int i = 0; i < TM; i++)
        #pragma unroll
        for (int j = 0; j < TN; j++) acc[i][j] = 0.f;

    for (int k0 = 0; k0 < K; k0 += BK) {
        for (int idx = tid; idx < BM * BK; idx += 256) {
            int r = idx / BK, k = idx % BK, gk = k0 + k;
            Xs[k][r] = (gk < K) ? X[(size_t)(m0 + r) * K + gk] : 0.f;
        }
        for (int idx = tid; idx < BN * BK; idx += 256) {
            int r = idx / BK, k = idx % BK, gk = k0 + k;
            Ws[k][r] = (gk < K) ? W[(size_t)(n0 + r) * K + gk] : 0.f;
        }
        __syncthreads();
        #pragma unroll
        for (int kk = 0; kk < BK; kk++) {
            float a[TM], bb[TN];
            #pragma unroll
            for (int i = 0; i < TM; i++) a[i] = Xs[kk][ty * TM + i];
            #pragma unroll
            for (int j = 0; j < TN; j++) bb[j] = Ws[kk][tx * TN + j];
            #pragma unroll
            for (int i = 0; i < TM; i++)
                #pragma unroll
                for (int j = 0; j < TN; j++)
                    acc[i][j] += a[i] * bb[j];
        }
        __syncthreads();
    }
    #pragma unroll
    for (int i = 0; i < TM; i++) {
        int m = m0 + ty * TM + i;
        #pragma unroll
        for (int j = 0; j < TN; j++) {
            int n = n0 + tx * TN + j;
            float v = fmaxf(acc[i][j] + bias[n], 0.f);
            Y[(size_t)m * N + n] = __float2bfloat16(v);
        }
    }
}

// ---------------------------------------------------------------------------
// bf16 MFMA GEMM: Y = act(X @ W^T + bias)
// X: M x K bf16 row-major.  W: N x K bf16 row-major.  K % 32 == 0.
// BM=128, BK=32. 256 threads = 4 waves arranged WM x WN; per-wave tile
// (BM/WM) x (BN/WN) in 16x16 fragments via mfma_f32_16x16x32_bf16.
// Verified lane maps (learn_hip m89/m91): A[m=lane&15][k=(lane>>4)*8+j],
// B[k][n]: n=lane&15, k=(lane>>4)*8+j;  C/D: col=lane&15, row=(lane>>4)*4+reg.
// Staging: global_load_lds width=16, LDS row-major contiguous (no pad —
// wave-uniform-base + lane*16 constraint).
// ---------------------------------------------------------------------------
template<int BN, int WM, int WN, int RELU, int OUT_BF16>
__global__ __launch_bounds__(256) void mfma_gemm(
    const short* __restrict__ A, const short* __restrict__ W,
    const float* __restrict__ bias, void* __restrict__ Y,
    int M, int N, int K)
{
    constexpr int BM = 128, BK = 32;
    constexpr int FM = BM / WM / 16;       // frag rows per wave
    constexpr int FN = BN / WN / 16;       // frag cols per wave
    constexpr int ACH = (BM * BK * 2) / 1024;   // A chunks of 1KB (=8)
    constexpr int BCH = (BN * BK * 2) / 1024;   // B chunks (8 or 4)

    __shared__ short As[BM * BK];
    __shared__ short Bs[BN * BK];

    const int tid  = threadIdx.x;
    const int wave = tid >> 6;
    const int lane = tid & 63;
    const int wm   = wave / WN;
    const int wn   = wave % WN;
    const int m0   = blockIdx.y * BM;
    const int n0   = blockIdx.x * BN;

    const int r16 = lane >> 2;        // row within a 16-row chunk
    const int c16 = (lane & 3) * 8;   // short offset of this lane's 16B

    float4v acc[FM][FN];
    #pragma unroll
    for (int i = 0; i < FM; i++)
        #pragma unroll
        for (int j = 0; j < FN; j++) acc[i][j] = (float4v)(0.f);

    for (int k0 = 0; k0 < K; k0 += BK) {
        // stage A tile: ACH/4 chunks per wave
        #pragma unroll
        for (int c = 0; c < ACH / 4; c++) {
            int chunk = wave * (ACH / 4) + c;
            int row   = chunk * 16 + r16;
            const short* src = A + (size_t)(m0 + row) * K + k0 + c16;
            __builtin_amdgcn_global_load_lds(
                (const GLOBAL_AS void*)src,
                (LDS_AS void*)(As + chunk * 512), 16, 0, 0);
        }
        // stage B tile
        #pragma unroll
        for (int c = 0; c < BCH / 4; c++) {
            int chunk = wave * (BCH / 4) + c;
            int row   = chunk * 16 + r16;
            const short* src = W + (size_t)(n0 + row) * K + k0 + c16;
            __builtin_amdgcn_global_load_lds(
                (const GLOBAL_AS void*)src,
                (LDS_AS void*)(Bs + chunk * 512), 16, 0, 0);
        }
        __syncthreads();   // drains vmcnt before barrier

        short8 a_frag[FM], b_frag[FN];
        const int kq = (lane >> 4) * 8;   // this lane's k offset
        #pragma unroll
        for (int fi = 0; fi < FM; fi++) {
            int m_local = wm * (BM / WM) + fi * 16 + (lane & 15);
            a_frag[fi] = *(const short8*)(As + m_local * BK + kq);
        }
        #pragma unroll
        for (int fj = 0; fj < FN; fj++) {
            int n_local = wn * (BN / WN) + fj * 16 + (lane & 15);
            b_frag[fj] = *(const short8*)(Bs + n_local * BK + kq);
        }
        #pragma unroll
        for (int fi = 0; fi < FM; fi++)
            #pragma unroll
            for (int fj = 0; fj < FN; fj++)
                acc[fi][fj] = __builtin_amdgcn_mfma_f32_16x16x32_bf16(
                    a_frag[fi], b_frag[fj], acc[fi][fj], 0, 0, 0);

        __syncthreads();   // LDS reuse protection
    }

    // epilogue
    #pragma unroll
    for (int fi = 0; fi < FM; fi++) {
        #pragma unroll
        for (int fj = 0; fj < FN; fj++) {
            int col   = n0 + wn * (BN / WN) + fj * 16 + (lane & 15);
            int rbase = m0 + wm * (BM / WM) + fi * 16 + (lane >> 4) * 4;
            float bv  = bias[col];
            #pragma unroll
            for (int r = 0; r < 4; r++) {
                float v = acc[fi][fj][r] + bv;
                if (RELU) v = fmaxf(v, 0.f);
                if (OUT_BF16)
                    ((__hip_bfloat16*)Y)[(size_t)(rbase + r) * N + col] =
                        __float2bfloat16(v);
                else
                    ((float*)Y)[(size_t)(rbase + r) * N + col] = v;
            }
        }
    }
}

// ---------------------------------------------------------------------------
// Embedding gather + pairwise interaction → R (bf16, stride 416, col415 = 0)
// ---------------------------------------------------------------------------
#define TS 68

__global__ __launch_bounds__(256) void interact_kernel(
    const float* __restrict__ x2,    // B x 64 fp32
    const int*   __restrict__ lS_i,  // NT x (B*LOOK)
    const float* __restrict__ emb,   // NT x VOCAB x 64
    __hip_bfloat16* __restrict__ R)  // B x 416 bf16
{
    __shared__ __align__(16) float T[(NT + 1) * TS];
    __shared__ int sidx[NT * LOOK];

    const int b   = blockIdx.x;
    const int tid = threadIdx.x;

    if (tid < NT * LOOK) {
        int tb = tid >> 2, l = tid & 3;
        sidx[tid] = lS_i[(size_t)tb * (BATCH * LOOK) + (size_t)b * LOOK + l];
    }
    if (tid < EMB_D) T[tid] = x2[(size_t)b * EMB_D + tid];
    __syncthreads();

    const int d = tid & 63;
    for (int tb = tid >> 6; tb < NT; tb += 4) {
        float s = 0.f;
        #pragma unroll
        for (int l = 0; l < LOOK; l++) {
            int row = sidx[tb * LOOK + l];
            s += emb[((size_t)tb * VOCAB_N + row) * EMB_D + d];
        }
        T[(tb + 1) * TS + d] = s;
    }
    __syncthreads();

    __hip_bfloat16* Rb = R + (size_t)b * 416;
    if (tid < EMB_D) Rb[tid] = __float2bfloat16(T[tid]);
    if (tid == 64)  Rb[415] = __float2bfloat16(0.f);

    for (int p = tid; p < 351; p += 256) {
        int i = (int)((1.0f + sqrtf(1.0f + 8.0f * (float)p)) * 0.5f);
        while (i * (i - 1) / 2 > p) --i;
        while ((i + 1) * i / 2 <= p) ++i;
        int j = p - i * (i - 1) / 2;
        const float* Ti = &T[i * TS];
        const float* Tj = &T[j * TS];
        float s = 0.f;
        #pragma unroll
        for (int k = 0; k < EMB_D; k++) s += Ti[k] * Tj[k];
        Rb[64 + p] = __float2bfloat16(s);
    }
}

// ---------------------------------------------------------------------------
// Final layer: out[b] = sigmoid(dot(z1[b,:256], W2) + b2). Wave per sample.
// ---------------------------------------------------------------------------
__global__ __launch_bounds__(256) void top_final(
    const float* __restrict__ z1, const float* __restrict__ W2,
    const float* __restrict__ b2, float* __restrict__ out)
{
    const int wave = threadIdx.x >> 6;
    const int lane = threadIdx.x & 63;
    const int b = blockIdx.x * 4 + wave;

    float s = 0.f;
    #pragma unroll
    for (int q = 0; q < 4; q++) {
        int k = q * 64 + lane;
        s += z1[(size_t)b * 256 + k] * W2[k];
    }
    #pragma unroll
    for (int off = 32; off; off >>= 1) s += __shfl_down(s, off, 64);
    if (lane == 0) out[b] = 1.f / (1.f + expf(-(s + b2[0])));
}

// ---------------------------------------------------------------------------
// Input order: 0 dense_x 1 lS_o 2 lS_i 3 emb | 4 bW0 5 bb0 6 tW0 7 tb0
//              8 bW1 9 bb1 10 tW1 11 tb1 | 12 bW2 13 bb2 14 tW2 15 tb2
// ---------------------------------------------------------------------------
extern "C" void kernel_launch(void* const* d_in, const int* in_sizes, int n_in,
                              void* d_out, int out_size, void* d_ws, size_t ws_size,
                              hipStream_t stream)
{
    const float* dense = (const float*)d_in[0];
    const int*   lS_i  = (const int*)d_in[2];
    const float* emb   = (const float*)d_in[3];
    const float* bW0 = (const float*)d_in[4];  const float* bb0 = (const float*)d_in[5];
    const float* tW0 = (const float*)d_in[6];  const float* tb0 = (const float*)d_in[7];
    const float* bW1 = (const float*)d_in[8];  const float* bb1 = (const float*)d_in[9];
    const float* tW1 = (const float*)d_in[10]; const float* tb1 = (const float*)d_in[11];
    const float* bW2 = (const float*)d_in[12]; const float* bb2 = (const float*)d_in[13];
    const float* tW2 = (const float*)d_in[14]; const float* tb2 = (const float*)d_in[15];
    float* out = (float*)d_out;

    // workspace layout
    char* p = (char*)d_ws;
    __hip_bfloat16* x0_bf = (__hip_bfloat16*)p;  p += (size_t)BATCH * 512 * 2;
    __hip_bfloat16* x1_bf = (__hip_bfloat16*)p;  p += (size_t)BATCH * 256 * 2;
    float*          x2_f  = (float*)p;           p += (size_t)BATCH * 64  * 4;
    __hip_bfloat16* R_bf  = (__hip_bfloat16*)p;  p += (size_t)BATCH * 416 * 2;
    __hip_bfloat16* z0_bf = (__hip_bfloat16*)p;  p += (size_t)BATCH * 512 * 2;
    float*          z1_f  = (float*)p;           p += (size_t)BATCH * 256 * 4;
    __hip_bfloat16* wb1   = (__hip_bfloat16*)p;  p += (size_t)256 * 512 * 2;
    __hip_bfloat16* wb2   = (__hip_bfloat16*)p;  p += (size_t)64  * 256 * 2;
    __hip_bfloat16* wt0   = (__hip_bfloat16*)p;  p += (size_t)512 * 416 * 2;
    __hip_bfloat16* wt1   = (__hip_bfloat16*)p;  p += (size_t)256 * 512 * 2;

    dim3 blk(256);

    // weight conversions (every call — ws is re-poisoned)
    conv_bf16<<<dim3((256 * 512 + 255) / 256), blk, 0, stream>>>(bW1, wb1, 256 * 512);
    conv_bf16<<<dim3((64 * 256 + 255) / 256),  blk, 0, stream>>>(bW2, wb2, 64 * 256);
    conv_bf16_pad<<<dim3((512 * 416 + 255) / 256), blk, 0, stream>>>(tW0, wt0, 512, 415, 416);
    conv_bf16<<<dim3((256 * 512 + 255) / 256), blk, 0, stream>>>(tW1, wt1, 256 * 512);

    // bottom MLP
    gemm_f32_k13<<<dim3(512 / 128, BATCH / 128), blk, 0, stream>>>(
        dense, bW0, bb0, x0_bf, BATCH, 512, 13);
    mfma_gemm<128, 2, 2, 1, 1><<<dim3(256 / 128, BATCH / 128), blk, 0, stream>>>(
        (const short*)x0_bf, (const short*)wb1, bb1, x1_bf, BATCH, 256, 512);
    mfma_gemm<64, 4, 1, 1, 0><<<dim3(1, BATCH / 128), blk, 0, stream>>>(
        (const short*)x1_bf, (const short*)wb2, bb2, x2_f, BATCH, 64, 256);

    // embedding + interaction (writes bf16 R, K padded to 416)
    interact_kernel<<<dim3(BATCH), blk, 0, stream>>>(x2_f, lS_i, emb, R_bf);

    // top MLP
    mfma_gemm<128, 2, 2, 1, 1><<<dim3(512 / 128, BATCH / 128), blk, 0, stream>>>(
        (const short*)R_bf, (const short*)wt0, tb0, z0_bf, BATCH, 512, 416);
    mfma_gemm<128, 2, 2, 1, 0><<<dim3(256 / 128, BATCH / 128), blk, 0, stream>>>(
        (const short*)z0_bf, (const short*)wt1, tb1, z1_f, BATCH, 256, 512);
    top_final<<<dim3(BATCH / 4), blk, 0, stream>>>(z1_f, tW2, tb2, out);
}